// Round 5
// baseline (95.195 us; speedup 1.0000x reference)
//
#include <hip/hip_runtime.h>
#include <math.h>

#define NPTS 4096
#define BLK 256
#define JGROUPS 16
#define RPT 16                          // rows per thread
#define PAIR_BLOCKS 2048                // 16 j-groups x 128 row-chunks
#define EV_BLOCKS 512
#define EVPT 8                          // events per thread
#define TOTAL_BLOCKS (PAIR_BLOCKS + EV_BLOCKS)   // 2560; every 5th block is an ev block
#define CNT_OFF (TOTAL_BLOCKS * 4)

// ---------------- fast erf: Abramowitz-Stegun 7.1.26, |err| <= 1.5e-7 ----------------
__device__ __forceinline__ float fast_erf(float x) {
    const float ax = fabsf(x);
    const float t  = __builtin_amdgcn_rcpf(fmaf(0.3275911f, ax, 1.0f));
    float p = fmaf(t, 1.061405429f, -1.453152027f);
    p = fmaf(t, p, 1.421413741f);
    p = fmaf(t, p, -0.284496736f);
    p = fmaf(t, p, 0.254829592f);
    p *= t;
    const float e = __expf(-ax * ax);
    const float r = fmaf(-p, e, 1.0f);
    return copysignf(r, x);
}

// ---------------- pair body: MODE 0 = all-direct, 1 = all-fold, 2 = mixed ----------------
template<int MODE>
__device__ __forceinline__ float pair_rows(const float2* __restrict__ z0,
                                           const float2* __restrict__ v0,
                                           int c, int j,
                                           float t0, float tn, float C) {
    const int jf = NPTS - 1 - j;
    float zjx_d = 0.f, zjy_d = 0.f, vjx_d = 0.f, vjy_d = 0.f;
    float zjx_f = 0.f, zjy_f = 0.f, vjx_f = 0.f, vjy_f = 0.f;
    if (MODE != 1) { const float2 z = z0[j];  const float2 v = v0[j];
                     zjx_d = z.x; zjy_d = z.y; vjx_d = v.x; vjy_d = v.y; }
    if (MODE != 0) { const float2 z = z0[jf]; const float2 v = v0[jf];
                     zjx_f = z.x; zjy_f = z.y; vjx_f = v.x; vjy_f = v.y; }

    float acc = 0.f;
    #pragma unroll 8
    for (int k = 0; k < RPT; ++k) {
        const int r = c * RPT + k;            // wave-uniform -> scalar loads
        float a, bb, m, n;
        bool valid = true;
        if (MODE == 0) {
            const float2 zr = z0[r], vr = v0[r];
            a = zr.x - zjx_d; bb = zr.y - zjy_d; m = vr.x - vjx_d; n = vr.y - vjy_d;
        } else if (MODE == 1) {
            const int rf = NPTS - 1 - r;
            const float2 zr = z0[rf], vr = v0[rf];
            a = zr.x - zjx_f; bb = zr.y - zjy_f; m = vr.x - vjx_f; n = vr.y - vjy_f;
        } else {
            const int rf = NPTS - 1 - r;
            const float2 zr  = z0[r],  vr  = v0[r];
            const float2 zrf = z0[rf], vrf = v0[rf];
            const bool fold = (j < r);
            a  = fold ? (zrf.x - zjx_f) : (zr.x - zjx_d);
            bb = fold ? (zrf.y - zjy_f) : (zr.y - zjy_d);
            m  = fold ? (vrf.x - vjx_f) : (vr.x - vjx_d);
            n  = fold ? (vrf.y - vjy_f) : (vr.y - vjy_d);
            valid = (j != r);
        }

        const float s2    = fmaf(m, m, n * n);
        const float inv_s = __builtin_amdgcn_rsqf(s2);
        const float cross = fmaf(bb, m, -a * n);
        const float am    = fmaf(a, m, bb * n);
        const float q     = cross * inv_s;
        const float E     = __expf(-q * q);
        const float e1    = fast_erf(fmaf(s2, t0, am) * inv_s);
        const float e2    = fast_erf(fmaf(s2, tn, am) * inv_s);

        float contrib = (C * E) * (e1 - e2) * inv_s;
        if (MODE == 2) contrib = valid ? contrib : 0.f;
        acc += contrib;
    }
    return acc;
}

// ---------------- fused kernel: interleaved ev/pair blocks; last block combines ----------------
__global__ __launch_bounds__(BLK, 8) void fused_kernel(
        const int* __restrict__ eu, const int* __restrict__ evn,
        const float* __restrict__ et,
        const float2* __restrict__ z0, const float2* __restrict__ v0,
        const float* __restrict__ beta_p, const float* __restrict__ t0_p,
        const float* __restrict__ tn_p,
        float* __restrict__ partial, unsigned* __restrict__ cnt,
        float* __restrict__ out, int nE) {
    const int bid = blockIdx.x;
    const float b = beta_p[0];
    float acc = 0.f;

    if (bid % 5 == 0) {
        // ----- event part: sum_e ||dz + dv*t||^2  (counts toward "subtract") -----
        const int ev_id = bid / 5;
        const int base  = ev_id * BLK + threadIdx.x;
        #pragma unroll
        for (int k0 = 0; k0 < EVPT; k0 += 4) {
            int   u[4], w[4];
            float t[4];
            bool  act[4];
            #pragma unroll
            for (int k = 0; k < 4; ++k) {
                const int idx = base + (k0 + k) * (EV_BLOCKS * BLK);
                act[k] = (idx < nE);
                const int safe = act[k] ? idx : 0;
                u[k] = eu[safe]; w[k] = evn[safe]; t[k] = et[safe];
            }
            float2 zu[4], zw[4], vu[4], vw[4];
            #pragma unroll
            for (int k = 0; k < 4; ++k) {
                zu[k] = z0[u[k]]; zw[k] = z0[w[k]];
                vu[k] = v0[u[k]]; vw[k] = v0[w[k]];
            }
            #pragma unroll
            for (int k = 0; k < 4; ++k) {
                const float dx = fmaf(vu[k].x - vw[k].x, t[k], zu[k].x - zw[k].x);
                const float dy = fmaf(vu[k].y - vw[k].y, t[k], zu[k].y - zw[k].y);
                const float d2 = fmaf(dx, dx, dy * dy);
                acc += act[k] ? d2 : 0.f;
            }
        }
    } else {
        // ----- pair part -----
        const int pair_id = bid - bid / 5 - 1;   // [0, PAIR_BLOCKS)
        const int g = pair_id & (JGROUPS - 1);
        const int c = pair_id >> 4;              // [0, 128)
        const int j = g * BLK + threadIdx.x;

        const float t0 = t0_p[0];
        const float tn = tn_p[0];
        const float C  = -0.88622692545275801365f * __expf(b);  // -sqrt(pi)/2 * e^b

        if (c < RPT * g)                 acc = pair_rows<0>(z0, v0, c, j, t0, tn, C);
        else if (c >= RPT * (g + 1))     acc = pair_rows<1>(z0, v0, c, j, t0, tn, C);
        else                             acc = pair_rows<2>(z0, v0, c, j, t0, tn, C);
    }

    // ----- block reduce -----
    #pragma unroll
    for (int off = 32; off > 0; off >>= 1)
        acc += __shfl_down(acc, off, 64);
    __shared__ float smem[BLK / 64];
    const int lane = threadIdx.x & 63;
    const int wid  = threadIdx.x >> 6;
    if (lane == 0) smem[wid] = acc;
    __syncthreads();

    __shared__ bool amLast;
    if (threadIdx.x == 0) {
        float s = 0.f;
        #pragma unroll
        for (int k = 0; k < BLK / 64; ++k) s += smem[k];
        __hip_atomic_store(&partial[bid], s, __ATOMIC_RELEASE, __HIP_MEMORY_SCOPE_AGENT);
        const unsigned old = __hip_atomic_fetch_add(cnt, 1u, __ATOMIC_ACQ_REL,
                                                    __HIP_MEMORY_SCOPE_AGENT);
        amLast = (old == TOTAL_BLOCKS - 1);
    }
    __syncthreads();

    if (amLast) {
        // deterministic final combine (fixed order, double precision)
        __shared__ double sd[BLK];
        double s = 0.0;
        #pragma unroll
        for (int k = 0; k < TOTAL_BLOCKS / BLK; ++k)
            s += (double)__hip_atomic_load(&partial[threadIdx.x + k * BLK],
                                           __ATOMIC_RELAXED, __HIP_MEMORY_SCOPE_AGENT);
        sd[threadIdx.x] = s;
        __syncthreads();
        for (int st = BLK / 2; st > 0; st >>= 1) {
            if (threadIdx.x < st) sd[threadIdx.x] += sd[threadIdx.x + st];
            __syncthreads();
        }
        if (threadIdx.x == 0)
            out[0] = (float)((double)nE * (double)b - sd[0]);
    }
}

extern "C" void kernel_launch(void* const* d_in, const int* in_sizes, int n_in,
                              void* d_out, int out_size, void* d_ws, size_t ws_size,
                              hipStream_t stream) {
    const int*    eu   = (const int*)d_in[0];
    const int*    evn  = (const int*)d_in[1];
    const float*  et   = (const float*)d_in[2];
    const float*  t0   = (const float*)d_in[3];
    const float*  tn   = (const float*)d_in[4];
    const float*  beta = (const float*)d_in[5];
    const float2* z0   = (const float2*)d_in[6];
    const float2* v0   = (const float2*)d_in[7];
    float* out = (float*)d_out;
    const int nE = in_sizes[0];

    float*    partial = (float*)d_ws;                      // TOTAL_BLOCKS floats
    unsigned* cnt     = (unsigned*)((char*)d_ws + CNT_OFF);

    hipMemsetAsync((void*)cnt, 0, sizeof(unsigned), stream);
    fused_kernel<<<TOTAL_BLOCKS, BLK, 0, stream>>>(eu, evn, et, z0, v0, beta, t0, tn,
                                                   partial, cnt, out, nE);
}

// Round 7
// 29.414 us; speedup vs baseline: 3.2363x; 3.2363x over previous
//
#include <hip/hip_runtime.h>
#include <math.h>

#define NPTS 4096
#define BLK 256
#define PAIR_BLOCKS 4096
#define EV_BLOCKS 1024
#define TOTAL_BLOCKS (PAIR_BLOCKS + EV_BLOCKS)   // 5120; every 5th block is an ev block
#define PAIR_CELLS (NPTS * NPTS / 2)             // 8,388,608 = 8 * PAIR_BLOCKS * BLK
#define VB 4                                     // ILP batch width

// ---------------- block-level float reduction (deterministic) ----------------
__device__ __forceinline__ float block_reduce_f(float v) {
    #pragma unroll
    for (int off = 32; off > 0; off >>= 1)
        v += __shfl_down(v, off, 64);
    __shared__ float smem[BLK / 64];
    const int lane = threadIdx.x & 63;
    const int wid  = threadIdx.x >> 6;
    if (lane == 0) smem[wid] = v;
    __syncthreads();
    float t = 0.f;
    if (threadIdx.x == 0) {
        #pragma unroll
        for (int w = 0; w < BLK / 64; ++w) t += smem[w];
    }
    return t;  // valid in thread 0 only
}

// ---------------- fused kernel: pair integral + event intensity ----------------
__global__ __launch_bounds__(BLK) void fused_kernel(
        const int* __restrict__ eu, const int* __restrict__ ev,
        const float* __restrict__ et,
        const float2* __restrict__ z0, const float2* __restrict__ v0,
        const float* __restrict__ beta_p, const float* __restrict__ t0_p,
        const float* __restrict__ tn_p,
        float* __restrict__ ev_partials, float* __restrict__ pair_partials,
        int nE) {
    const int bid = blockIdx.x;
    const bool is_ev = (bid % 5 == 0);

    if (is_ev) {
        // ----- event part: sum_e ||dz + dv*t||^2 (identical to R2) -----
        const int ev_id = bid / 5;                       // [0, EV_BLOCKS)
        float acc = 0.f;
        for (int i = ev_id * BLK + threadIdx.x; i < nE; i += EV_BLOCKS * BLK) {
            const int a = eu[i];
            const int b = ev[i];
            const float t = et[i];
            const float2 za = z0[a], zb = z0[b];
            const float2 va = v0[a], vb = v0[b];
            const float dx = fmaf(va.x - vb.x, t, za.x - zb.x);
            const float dy = fmaf(va.y - vb.y, t, za.y - zb.y);
            acc += fmaf(dx, dx, dy * dy);
        }
        const float r = block_reduce_f(acc);
        if (threadIdx.x == 0) ev_partials[ev_id] = r;
    } else {
        // ----- pair part: each unordered pair exactly once; V=4 stage-batched ILP -----
        const int pair_id = bid - (bid / 5 + 1);         // [0, PAIR_BLOCKS)
        const float b  = beta_p[0];
        const float t0 = t0_p[0];
        const float tn = tn_p[0];
        const float C  = -0.88622692545275801365f * __expf(b);   // -sqrt(pi)/2 * e^b

        const int tid0 = pair_id * BLK + threadIdx.x;    // idx for it=0; stride 2^20 per it
        const int j    = tid0 & (NPTS - 1);              // fixed per thread
        const int i0   = tid0 >> 12;                     // [0, 256); i = i0 + it*256
        const int jf   = NPTS - 1 - j;
        const float2 zj  = z0[j],  vj  = v0[j];
        const float2 zjf = z0[jf], vjf = v0[jf];

        float acc = 0.f;
        #pragma unroll
        for (int half = 0; half < 2; ++half) {
            // ---- stage 1: coords, loads, operand assembly (4 independent cells) ----
            float a[VB], bbv[VB], m[VB], n[VB];
            bool  ok[VB];
            #pragma unroll
            for (int k = 0; k < VB; ++k) {
                const int it = half * VB + k;
                const int i  = i0 + it * 256;            // wave-uniform value
                const bool fold = (j < i);               // per-lane
                ok[k] = (j != i);
                const int ii = fold ? (NPTS - 1 - i) : i;   // <=2 distinct per wave
                const float2 zi = z0[ii];
                const float2 vi = v0[ii];
                const float zjx = fold ? zjf.x : zj.x;
                const float zjy = fold ? zjf.y : zj.y;
                const float vjx = fold ? vjf.x : vj.x;
                const float vjy = fold ? vjf.y : vj.y;
                a[k]   = zi.x - zjx;
                bbv[k] = zi.y - zjy;
                m[k]   = vi.x - vjx;
                n[k]   = vi.y - vjy;
            }
            // ---- stage 2: batched algebra ----
            float s2[VB], inv_s[VB], am[VB], q[VB];
            #pragma unroll
            for (int k = 0; k < VB; ++k) s2[k] = fmaf(m[k], m[k], n[k] * n[k]);
            #pragma unroll
            for (int k = 0; k < VB; ++k) inv_s[k] = __builtin_amdgcn_rsqf(s2[k]);
            #pragma unroll
            for (int k = 0; k < VB; ++k) am[k] = fmaf(a[k], m[k], bbv[k] * n[k]);
            #pragma unroll
            for (int k = 0; k < VB; ++k) q[k] = fmaf(bbv[k], m[k], -a[k] * n[k]) * inv_s[k];
            // ---- stage 3: batched erf args ----
            float x1[VB], x2[VB];
            #pragma unroll
            for (int k = 0; k < VB; ++k) x1[k] = fmaf(s2[k], t0, am[k]) * inv_s[k];
            #pragma unroll
            for (int k = 0; k < VB; ++k) x2[k] = fmaf(s2[k], tn, am[k]) * inv_s[k];
            // ---- stage 4: batched fast_erf (A&S 7.1.26) for x1, x2 ----
            float t1[VB], t2[VB], g1[VB], g2[VB];
            #pragma unroll
            for (int k = 0; k < VB; ++k) t1[k] = __builtin_amdgcn_rcpf(fmaf(0.3275911f, fabsf(x1[k]), 1.0f));
            #pragma unroll
            for (int k = 0; k < VB; ++k) t2[k] = __builtin_amdgcn_rcpf(fmaf(0.3275911f, fabsf(x2[k]), 1.0f));
            #pragma unroll
            for (int k = 0; k < VB; ++k) g1[k] = __expf(-x1[k] * x1[k]);
            #pragma unroll
            for (int k = 0; k < VB; ++k) g2[k] = __expf(-x2[k] * x2[k]);
            float e1[VB], e2[VB];
            #pragma unroll
            for (int k = 0; k < VB; ++k) {
                float p = fmaf(t1[k], 1.061405429f, -1.453152027f);
                p = fmaf(t1[k], p, 1.421413741f);
                p = fmaf(t1[k], p, -0.284496736f);
                p = fmaf(t1[k], p, 0.254829592f);
                p *= t1[k];
                e1[k] = copysignf(fmaf(-p, g1[k], 1.0f), x1[k]);
            }
            #pragma unroll
            for (int k = 0; k < VB; ++k) {
                float p = fmaf(t2[k], 1.061405429f, -1.453152027f);
                p = fmaf(t2[k], p, 1.421413741f);
                p = fmaf(t2[k], p, -0.284496736f);
                p = fmaf(t2[k], p, 0.254829592f);
                p *= t2[k];
                e2[k] = copysignf(fmaf(-p, g2[k], 1.0f), x2[k]);
            }
            // ---- stage 5: batched Gaussian factor + accumulate (select kills diag NaN) ----
            float E[VB];
            #pragma unroll
            for (int k = 0; k < VB; ++k) E[k] = __expf(-q[k] * q[k]);
            #pragma unroll
            for (int k = 0; k < VB; ++k) {
                const float contrib = (C * E[k]) * (e1[k] - e2[k]) * inv_s[k];
                acc += ok[k] ? contrib : 0.f;
            }
        }
        const float r = block_reduce_f(acc);
        if (threadIdx.x == 0) pair_partials[pair_id] = r;
    }
}

// ---------------- final combine (double precision, deterministic) ----------------
__global__ void final_kernel(const float* __restrict__ evp, const float* __restrict__ pp,
                             const float* __restrict__ beta_p, float* __restrict__ out,
                             int nE) {
    __shared__ double sd[BLK];
    double se = 0.0;
    for (int i = threadIdx.x; i < EV_BLOCKS; i += BLK) se += (double)evp[i];
    double sp = 0.0;
    for (int i = threadIdx.x; i < PAIR_BLOCKS; i += BLK) sp += (double)pp[i];
    sd[threadIdx.x] = se + sp;   // (sum d2) + non_event_intensity
    __syncthreads();
    for (int s = BLK / 2; s > 0; s >>= 1) {
        if (threadIdx.x < s) sd[threadIdx.x] += sd[threadIdx.x + s];
        __syncthreads();
    }
    if (threadIdx.x == 0) {
        out[0] = (float)((double)nE * (double)beta_p[0] - sd[0]);
    }
}

extern "C" void kernel_launch(void* const* d_in, const int* in_sizes, int n_in,
                              void* d_out, int out_size, void* d_ws, size_t ws_size,
                              hipStream_t stream) {
    const int*    eu   = (const int*)d_in[0];
    const int*    ev   = (const int*)d_in[1];
    const float*  et   = (const float*)d_in[2];
    const float*  t0   = (const float*)d_in[3];
    const float*  tn   = (const float*)d_in[4];
    const float*  beta = (const float*)d_in[5];
    const float2* z0   = (const float2*)d_in[6];
    const float2* v0   = (const float2*)d_in[7];
    float* out = (float*)d_out;
    const int nE = in_sizes[0];

    float* ev_partials   = (float*)d_ws;                  // EV_BLOCKS floats
    float* pair_partials = ev_partials + EV_BLOCKS;       // PAIR_BLOCKS floats

    fused_kernel<<<TOTAL_BLOCKS, BLK, 0, stream>>>(eu, ev, et, z0, v0, beta, t0, tn,
                                                   ev_partials, pair_partials, nE);
    final_kernel<<<1, BLK, 0, stream>>>(ev_partials, pair_partials, beta, out, nE);
}